// Round 2
// baseline (675.550 us; speedup 1.0000x reference)
//
#include <hip/hip_runtime.h>
#include <hip/hip_bf16.h>
#include <hip/hip_fp16.h>

typedef _Float16 f16x8 __attribute__((ext_vector_type(8)));
typedef float    f32x4 __attribute__((ext_vector_type(4)));

#define MFMA16(a, b, c) __builtin_amdgcn_mfma_f32_16x16x32_f16(a, b, c, 0, 0, 0)

static constexpr int BN   = 8;     // batch
static constexpr int CIN  = 512;   // channels
static constexpr int NHW  = 4096;  // H*W
static constexpr int OD   = 256;   // INTER

// XOR-swizzled byte offsets (T2): row stride 512B (Kl) / 128B (Vl, Pl)
#define KSWZ(r, cb) ((((r) << 9) + (cb)) ^ (((r) & 7) << 4))
#define VSWZ(r, cb) ((((r) << 7) + (cb)) ^ (((r) & 7) << 4))
#define PSWZ(r, cb) ((((r) << 7) + (cb)) ^ (((r) & 7) << 4))

__device__ __forceinline__ f16x8 cvt8(const float4 a, const float4 b) {
    f16x8 r;
    r[0] = (_Float16)a.x; r[1] = (_Float16)a.y; r[2] = (_Float16)a.z; r[3] = (_Float16)a.w;
    r[4] = (_Float16)b.x; r[5] = (_Float16)b.y; r[6] = (_Float16)b.z; r[7] = (_Float16)b.w;
    return r;
}

// ---------------------------------------------------------------------------
// Prep: T[b][n][o] = sum_c x[b][c][n] * w[o][c] + bias[o], stored as f16.
// ---------------------------------------------------------------------------
__global__ __launch_bounds__(256)
void prep_gemm(const float* __restrict__ xq, const float* __restrict__ xs,
               const float* __restrict__ thw, const float* __restrict__ thb,
               const float* __restrict__ phw, const float* __restrict__ phb,
               _Float16* __restrict__ Qws, _Float16* __restrict__ Kws)
{
    const int nt = blockIdx.x, ot = blockIdx.y, z = blockIdx.z;
    const int b = z >> 1, sel = z & 1;
    const float* x    = (sel ? xs : xq) + (size_t)b * CIN * NHW;
    const float* w    = sel ? phw : thw;
    const float* bias = sel ? phb : thb;
    _Float16*   out   = (sel ? Kws : Qws) + (size_t)b * NHW * OD;
    const int n0 = nt * 64, o0 = ot * 64;

    __shared__ __align__(16) _Float16 Xs[64][72];
    __shared__ __align__(16) _Float16 Ws[64][72];

    const int t    = threadIdx.x;
    const int lane = t & 63, wave = t >> 6;
    const int l16  = lane & 15, lh = lane >> 4;

    f32x4 acc[4] = {};

    for (int c0 = 0; c0 < CIN; c0 += 64) {
        #pragma unroll
        for (int rep = 0; rep < 4; ++rep) {
            const int ci = rep * 16 + (t >> 4);
            const int nl = (t & 15) * 4;
            const float4 v = *(const float4*)&x[(size_t)(c0 + ci) * NHW + n0 + nl];
            Xs[nl + 0][ci] = (_Float16)v.x;
            Xs[nl + 1][ci] = (_Float16)v.y;
            Xs[nl + 2][ci] = (_Float16)v.z;
            Xs[nl + 3][ci] = (_Float16)v.w;
        }
        {
            const int oi = t >> 2;
            const int cl = (t & 3) * 16;
            const float4* wp = (const float4*)&w[(size_t)(o0 + oi) * CIN + c0 + cl];
            float4 a0 = wp[0], a1 = wp[1], a2 = wp[2], a3 = wp[3];
            *(f16x8*)&Ws[oi][cl]     = cvt8(a0, a1);
            *(f16x8*)&Ws[oi][cl + 8] = cvt8(a2, a3);
        }
        __syncthreads();

        #pragma unroll
        for (int kk = 0; kk < 2; ++kk) {
            const f16x8 afrag = *(const f16x8*)&Xs[wave * 16 + l16][kk * 32 + lh * 8];
            #pragma unroll
            for (int oo = 0; oo < 4; ++oo) {
                const f16x8 bfrag = *(const f16x8*)&Ws[oo * 16 + l16][kk * 32 + lh * 8];
                acc[oo] = MFMA16(afrag, bfrag, acc[oo]);
            }
        }
        __syncthreads();
    }

    #pragma unroll
    for (int oo = 0; oo < 4; ++oo) {
        const float bi = bias[o0 + oo * 16 + l16];
        #pragma unroll
        for (int r = 0; r < 4; ++r) {
            const int n = n0 + wave * 16 + lh * 4 + r;
            out[(size_t)n * OD + o0 + oo * 16 + l16] = (_Float16)(acc[oo][r] + bi);
        }
    }
}

// ---------------------------------------------------------------------------
// Compact mask: ordered (deterministic) compaction of unmasked support pixels.
// 1 block per batch, 256 threads. idx[b][k] = source n of k-th unmasked pixel,
// vmask[b][k] = 1 for real, 0 for pad up to Npad (multiple of 64).
// nbArr[b*2] = Nb, nbArr[b*2+1] = Npad/64.
// ---------------------------------------------------------------------------
__global__ __launch_bounds__(256)
void compact_mask(const float* __restrict__ mask, int* __restrict__ idx,
                  float* __restrict__ vmask, int* __restrict__ nbArr)
{
    const int b = blockIdx.x, t = threadIdx.x;
    const float* mb = mask + (size_t)b * NHW;
    __shared__ int cnt[256];
    __shared__ int pre[257];

    const int base = t * 16;
    float mv[16];
    int c = 0;
    #pragma unroll
    for (int i = 0; i < 16; ++i) { mv[i] = mb[base + i]; c += (mv[i] != 0.0f); }
    cnt[t] = c;
    __syncthreads();
    if (t == 0) {
        int s = 0;
        for (int i = 0; i < 256; ++i) { pre[i] = s; s += cnt[i]; }
        pre[256] = s;
    }
    __syncthreads();
    int o = pre[t];
    #pragma unroll
    for (int i = 0; i < 16; ++i) {
        if (mv[i] != 0.0f) {
            idx[(size_t)b * NHW + o]   = base + i;
            vmask[(size_t)b * NHW + o] = 1.0f;
            ++o;
        }
    }
    const int Nb = pre[256];
    const int Npad = (Nb + 63) & ~63;
    for (int k = Nb + t; k < Npad; k += 256) {
        idx[(size_t)b * NHW + k]   = 0;
        vmask[(size_t)b * NHW + k] = 0.0f;
    }
    if (t == 0) { nbArr[b * 2] = Nb; nbArr[b * 2 + 1] = Npad >> 6; }
}

// ---------------------------------------------------------------------------
// Gather V into compacted f16 layout: Vc[b][o][k] = emb[b][o][idx[b][k]], 0 for pad.
// grid (64, 8), block 256; blocks past Npad exit.
// ---------------------------------------------------------------------------
__global__ __launch_bounds__(256)
void gather_v(const float* __restrict__ emb, const int* __restrict__ idx,
              const int* __restrict__ nbArr, _Float16* __restrict__ Vc)
{
    const int b = blockIdx.y;
    const int k0 = blockIdx.x * 64;
    const int ntile = nbArr[b * 2 + 1];
    if (k0 >= ntile * 64) return;
    const int Nb = nbArr[b * 2];
    const int t = threadIdx.x, kl = t & 63, ow = t >> 6;
    const int k = k0 + kl;
    const int ii = idx[(size_t)b * NHW + k];
    const bool valid = k < Nb;
    const float* eb = emb + (size_t)b * OD * NHW;
    _Float16* vb = Vc + (size_t)b * OD * NHW;
    for (int o = ow; o < OD; o += 4) {
        float v = valid ? eb[(size_t)o * NHW + ii] : 0.0f;
        vb[(size_t)o * NHW + k] = (_Float16)v;
    }
}

// ---------------------------------------------------------------------------
// Fused flash attention over compacted support pixels.
// grid 512 (b = bid&7, qt = bid>>3), block 256 (4 waves x 16 q-rows).
// LDS 72 KB -> 2 blocks/CU.
// ---------------------------------------------------------------------------
__global__ __launch_bounds__(256)
void flash_attn(const _Float16* __restrict__ Qws, const _Float16* __restrict__ Kws,
                const _Float16* __restrict__ Vc, const float* __restrict__ vmask,
                const int* __restrict__ idx, const int* __restrict__ nbArr,
                float* __restrict__ outp)
{
    const int bid = blockIdx.x;
    const int b = bid & 7, qt = bid >> 3;
    const int t = threadIdx.x, lane = t & 63, wave = t >> 6;
    const int l16 = lane & 15, lh = lane >> 4;

    __shared__ __align__(16) char Kl[64 * 512];    // 32 KB, swizzled [j][o] f16
    __shared__ __align__(16) char Vl[256 * 128];   // 32 KB, swizzled [o][j] f16
    __shared__ __align__(16) char Pl[4][2048];     // 8 KB, per-wave swizzled [i][j] f16

    const _Float16* Qb = Qws + (size_t)b * NHW * OD;
    const _Float16* Kb = Kws + (size_t)b * NHW * OD;
    const _Float16* Vb = Vc  + (size_t)b * OD * NHW;
    const float*    mv = vmask + (size_t)b * NHW;
    const int*    kidx = idx + (size_t)b * NHW;
    const int    ntile = nbArr[b * 2 + 1];

    // Q fragments for this wave's 16 rows, held for the whole kernel
    f16x8 qf[8];
    {
        const _Float16* qrow = Qb + (size_t)(qt * 64 + wave * 16 + l16) * OD + lh * 8;
        #pragma unroll
        for (int kk = 0; kk < 8; ++kk)
            qf[kk] = *(const f16x8*)(qrow + kk * 32);
    }

    f32x4 accO[16] = {};
    float M[4] = { -INFINITY, -INFINITY, -INFINITY, -INFINITY };
    float L[4] = { 0.f, 0.f, 0.f, 0.f };

    #pragma unroll 1
    for (int jt = 0; jt < ntile; ++jt) {
        // ---- stage K tile (gathered rows), 64 x 256 f16
        #pragma unroll
        for (int r = 0; r < 8; ++r) {
            const int p = r * 256 + t;
            const int row = p >> 5, cs = (p & 31) * 8;
            const int nsrc = kidx[jt * 64 + row];
            *(f16x8*)(Kl + KSWZ(row, cs * 2)) = *(const f16x8*)(Kb + (size_t)nsrc * OD + cs);
        }
        // ---- stage V tile from compacted f16 Vc
        #pragma unroll
        for (int r = 0; r < 8; ++r) {
            const int p = r * 256 + t;
            const int o = p >> 3, j0 = (p & 7) * 8;
            *(f16x8*)(Vl + VSWZ(o, j0 * 2)) = *(const f16x8*)(Vb + (size_t)o * NHW + jt * 64 + j0);
        }
        __syncthreads();

        // ---- S = Q K^T : 16x64 per wave
        f32x4 S[4] = {};
        #pragma unroll
        for (int ct = 0; ct < 4; ++ct) {
            #pragma unroll
            for (int kk = 0; kk < 8; ++kk) {
                const f16x8 kf = *(const f16x8*)(Kl + KSWZ(ct * 16 + l16, kk * 64 + lh * 16));
                S[ct] = MFMA16(qf[kk], kf, S[ct]);
            }
        }

        // ---- mask + temperature
        float logit[4][4];
        #pragma unroll
        for (int ct = 0; ct < 4; ++ct) {
            const float m = mv[jt * 64 + ct * 16 + l16];
            #pragma unroll
            for (int r = 0; r < 4; ++r)
                logit[ct][r] = (m != 0.0f) ? S[ct][r] * 0.25f : -2.5e8f;
        }

        // ---- row max + deferred rescale (T13, THR=8)
        float tmax[4];
        #pragma unroll
        for (int r = 0; r < 4; ++r) {
            float tm = fmaxf(fmaxf(logit[0][r], logit[1][r]),
                             fmaxf(logit[2][r], logit[3][r]));
            tm = fmaxf(tm, __shfl_xor(tm, 1));
            tm = fmaxf(tm, __shfl_xor(tm, 2));
            tm = fmaxf(tm, __shfl_xor(tm, 4));
            tm = fmaxf(tm, __shfl_xor(tm, 8));
            tmax[r] = tm;
        }
        bool grow = false;
        #pragma unroll
        for (int r = 0; r < 4; ++r) grow = grow || (tmax[r] > M[r] + 8.0f);
        if (__any(grow)) {
            float fac[4];
            #pragma unroll
            for (int r = 0; r < 4; ++r) {
                const float nm = fmaxf(M[r], tmax[r]);
                fac[r] = __expf(M[r] - nm);
                M[r] = nm;
                L[r] *= fac[r];
            }
            #pragma unroll
            for (int oo = 0; oo < 16; ++oo)
                #pragma unroll
                for (int r = 0; r < 4; ++r)
                    accO[oo][r] *= fac[r];
        }

        // ---- P = exp(logit - M), row sums
        float rowsum[4] = { 0.f, 0.f, 0.f, 0.f };
        _Float16 ph[4][4];
        #pragma unroll
        for (int ct = 0; ct < 4; ++ct)
            #pragma unroll
            for (int r = 0; r < 4; ++r) {
                const float p = __expf(logit[ct][r] - M[r]);
                rowsum[r] += p;
                ph[ct][r] = (_Float16)p;
            }
        #pragma unroll
        for (int r = 0; r < 4; ++r) {
            float s = rowsum[r];
            s += __shfl_xor(s, 1);
            s += __shfl_xor(s, 2);
            s += __shfl_xor(s, 4);
            s += __shfl_xor(s, 8);
            L[r] += s;
        }

        // ---- P -> per-wave LDS (wave-local; no barrier needed)
        #pragma unroll
        for (int ct = 0; ct < 4; ++ct)
            #pragma unroll
            for (int r = 0; r < 4; ++r)
                *(_Float16*)(Pl[wave] + PSWZ(lh * 4 + r, (ct * 16 + l16) * 2)) = ph[ct][r];

        // ---- O += P V
        f16x8 pf[2];
        #pragma unroll
        for (int kc = 0; kc < 2; ++kc)
            pf[kc] = *(const f16x8*)(Pl[wave] + PSWZ(l16, kc * 64 + lh * 16));
        #pragma unroll
        for (int oo = 0; oo < 16; ++oo) {
            #pragma unroll
            for (int kc = 0; kc < 2; ++kc) {
                const f16x8 vf = *(const f16x8*)(Vl + VSWZ(oo * 16 + l16, kc * 64 + lh * 16));
                accO[oo] = MFMA16(pf[kc], vf, accO[oo]);
            }
        }
        __syncthreads();
    }

    // ---- epilogue
    float rl[4];
    #pragma unroll
    for (int r = 0; r < 4; ++r) rl[r] = 1.0f / fmaxf(L[r], 1e-30f);
    #pragma unroll
    for (int oo = 0; oo < 16; ++oo) {
        const int o = oo * 16 + l16;
        #pragma unroll
        for (int r = 0; r < 4; ++r) {
            const int n = qt * 64 + wave * 16 + lh * 4 + r;
            outp[((size_t)b * OD + o) * NHW + n] = accO[oo][r] * rl[r];
        }
    }
}

extern "C" void kernel_launch(void* const* d_in, const int* in_sizes, int n_in,
                              void* d_out, int out_size, void* d_ws, size_t ws_size,
                              hipStream_t stream) {
    const float* xq   = (const float*)d_in[0];
    const float* xs   = (const float*)d_in[1];
    const float* emb  = (const float*)d_in[2];
    const float* mask = (const float*)d_in[3];
    const float* thw  = (const float*)d_in[4];
    const float* thb  = (const float*)d_in[5];
    const float* phw  = (const float*)d_in[6];
    const float* phb  = (const float*)d_in[7];
    float* out = (float*)d_out;

    const size_t szT = (size_t)BN * NHW * OD;  // elements per f16 tensor
    _Float16* Qws = (_Float16*)d_ws;
    _Float16* Kws = Qws + szT;
    _Float16* Vc  = Kws + szT;
    int*   idxArr   = (int*)(Vc + szT);
    float* vmaskArr = (float*)(idxArr + (size_t)BN * NHW);
    int*   nbArr    = (int*)(vmaskArr + (size_t)BN * NHW);

    prep_gemm<<<dim3(64, 4, 16), 256, 0, stream>>>(xq, xs, thw, thb, phw, phb, Qws, Kws);
    compact_mask<<<dim3(BN), 256, 0, stream>>>(mask, idxArr, vmaskArr, nbArr);
    gather_v<<<dim3(64, BN), 256, 0, stream>>>(emb, idxArr, nbArr, Vc);
    flash_attn<<<dim3(512), 256, 0, stream>>>(Qws, Kws, Vc, vmaskArr, idxArr, nbArr, out);
}

// Round 4
// 237.324 us; speedup vs baseline: 2.8465x; 2.8465x over previous
//
#include <hip/hip_runtime.h>
#include <hip/hip_fp16.h>

typedef _Float16 f16x8 __attribute__((ext_vector_type(8)));
typedef _Float16 f16x4 __attribute__((ext_vector_type(4)));
typedef float    f32x4 __attribute__((ext_vector_type(4)));

#define MFMA16(a, b, c) __builtin_amdgcn_mfma_f32_16x16x32_f16(a, b, c, 0, 0, 0)

static constexpr int BN   = 8;
static constexpr int CIN  = 512;
static constexpr int NHW  = 4096;
static constexpr int OD   = 256;
static constexpr int KBLK = 32;

// 128B-row XOR swizzle (prep LDS tiles)
#define RSWZ(row, cb) ((((row) << 7)) + ((cb) ^ (((row) & 7) << 4)))

__device__ __forceinline__ f16x8 cvt8(const float4 a, const float4 b) {
    f16x8 r;
    r[0] = (_Float16)a.x; r[1] = (_Float16)a.y; r[2] = (_Float16)a.z; r[3] = (_Float16)a.w;
    r[4] = (_Float16)b.x; r[5] = (_Float16)b.y; r[6] = (_Float16)b.z; r[7] = (_Float16)b.w;
    return r;
}

// ---------------------------------------------------------------------------
// Convert theta/phi weights to f16 once. wf[sel][o][c], 256x512 each.
// ---------------------------------------------------------------------------
__global__ __launch_bounds__(256)
void wcvt(const float* __restrict__ thw, const float* __restrict__ phw,
          _Float16* __restrict__ wf)
{
    const int i = blockIdx.x * 256 + threadIdx.x;   // 32768 float4 units
    const float4 a = ((const float4*)thw)[i];
    const float4 b = ((const float4*)phw)[i];
    f16x4 ra, rb;
    ra[0] = (_Float16)a.x; ra[1] = (_Float16)a.y; ra[2] = (_Float16)a.z; ra[3] = (_Float16)a.w;
    rb[0] = (_Float16)b.x; rb[1] = (_Float16)b.y; rb[2] = (_Float16)b.z; rb[3] = (_Float16)b.w;
    *(f16x4*)(wf + (size_t)i * 4)          = ra;
    *(f16x4*)(wf + 131072 + (size_t)i * 4) = rb;
}

// ---------------------------------------------------------------------------
// Prep: T[b][n][o] = sum_c x[b][c][n]*w[o][c] + bias[o] -> f16 [n][256].
// grid (64 nt, 16 = b*2+sel), block 256. x read ONCE; full o=256 per block.
// ---------------------------------------------------------------------------
__global__ __launch_bounds__(256)
void prep_gemm(const float* __restrict__ xq, const float* __restrict__ xs,
               const _Float16* __restrict__ wf,
               const float* __restrict__ thb, const float* __restrict__ phb,
               _Float16* __restrict__ Qws, _Float16* __restrict__ Kws)
{
    const int nt = blockIdx.x, z = blockIdx.y;
    const int b = z >> 1, sel = z & 1;
    const float* x        = (sel ? xs : xq) + (size_t)b * CIN * NHW;
    const _Float16* w     = wf + (size_t)sel * (OD * CIN);
    const float* bias     = sel ? phb : thb;
    _Float16* out         = (sel ? Kws : Qws) + (size_t)b * NHW * OD;
    const int n0 = nt * 64;

    __shared__ __align__(16) char Xs[64 * 128];    // [n][c-chunk 64] f16, swizzled
    __shared__ __align__(16) char Ws[256 * 128];   // [o][c-chunk 64] f16, swizzled

    const int t    = threadIdx.x;
    const int lane = t & 63, wave = t >> 6;
    const int l16  = lane & 15, lh = lane >> 4;

    f32x4 acc[4][4] = {};   // [oo][nn]: rows o = wave*64+oo*16+4lh+r, cols n = nn*16+l16

    for (int c0 = 0; c0 < CIN; c0 += 64) {
        // stage Xs: transpose x[c][n] -> Xs[n][c]
        #pragma unroll
        for (int rep = 0; rep < 4; ++rep) {
            const int ci = rep * 16 + (t >> 4);
            const int nl = (t & 15) * 4;
            const float4 v = *(const float4*)&x[(size_t)(c0 + ci) * NHW + n0 + nl];
            *(_Float16*)(Xs + RSWZ(nl + 0, ci * 2)) = (_Float16)v.x;
            *(_Float16*)(Xs + RSWZ(nl + 1, ci * 2)) = (_Float16)v.y;
            *(_Float16*)(Xs + RSWZ(nl + 2, ci * 2)) = (_Float16)v.z;
            *(_Float16*)(Xs + RSWZ(nl + 3, ci * 2)) = (_Float16)v.w;
        }
        // stage Ws: all 256 o rows, this c-chunk (f16 source)
        #pragma unroll
        for (int r = 0; r < 8; ++r) {
            const int u = r * 256 + t;
            const int o = u >> 3, cs8 = (u & 7) * 8;
            const f16x8 v = *(const f16x8*)(w + (size_t)o * CIN + c0 + cs8);
            *(f16x8*)(Ws + RSWZ(o, cs8 * 2)) = v;
        }
        __syncthreads();

        #pragma unroll
        for (int kk = 0; kk < 2; ++kk) {
            f16x8 af[4];
            #pragma unroll
            for (int oo = 0; oo < 4; ++oo)
                af[oo] = *(const f16x8*)(Ws + RSWZ(wave * 64 + oo * 16 + l16, kk * 64 + lh * 16));
            #pragma unroll
            for (int nn = 0; nn < 4; ++nn) {
                const f16x8 bf = *(const f16x8*)(Xs + RSWZ(nn * 16 + l16, kk * 64 + lh * 16));
                #pragma unroll
                for (int oo = 0; oo < 4; ++oo)
                    acc[oo][nn] = MFMA16(af[oo], bf, acc[oo][nn]);
            }
        }
        __syncthreads();
    }

    // epilogue: lane holds o = wave*64+oo*16+lh*4+r, n = nn*16+l16 -> f16x4 stores
    #pragma unroll
    for (int oo = 0; oo < 4; ++oo) {
        const float4 bi = *(const float4*)&bias[wave * 64 + oo * 16 + lh * 4];
        #pragma unroll
        for (int nn = 0; nn < 4; ++nn) {
            f16x4 v;
            v[0] = (_Float16)(acc[oo][nn][0] + bi.x);
            v[1] = (_Float16)(acc[oo][nn][1] + bi.y);
            v[2] = (_Float16)(acc[oo][nn][2] + bi.z);
            v[3] = (_Float16)(acc[oo][nn][3] + bi.w);
            const int n = n0 + nn * 16 + l16;
            *(f16x4*)&out[(size_t)n * OD + wave * 64 + oo * 16 + lh * 4] = v;
        }
    }
}

// ---------------------------------------------------------------------------
// Compact mask (ordered). idx[b][k] = source n of k-th unmasked pixel (0-pad
// to Npad=ceil64(Nb)); nbArr[b*2]=Nb, nbArr[b*2+1]=Npad/32 (flash tile count).
// ---------------------------------------------------------------------------
__global__ __launch_bounds__(256)
void compact_mask(const float* __restrict__ mask, int* __restrict__ idx,
                  int* __restrict__ nbArr)
{
    const int b = blockIdx.x, t = threadIdx.x;
    const float* mb = mask + (size_t)b * NHW;
    __shared__ int cnt[256];
    __shared__ int pre[257];

    const int base = t * 16;
    float mv[16];
    int c = 0;
    #pragma unroll
    for (int i = 0; i < 16; ++i) { mv[i] = mb[base + i]; c += (mv[i] != 0.0f); }
    cnt[t] = c;
    __syncthreads();
    if (t == 0) {
        int s = 0;
        for (int i = 0; i < 256; ++i) { pre[i] = s; s += cnt[i]; }
        pre[256] = s;
    }
    __syncthreads();
    int o = pre[t];
    #pragma unroll
    for (int i = 0; i < 16; ++i)
        if (mv[i] != 0.0f) idx[(size_t)b * NHW + o++] = base + i;

    const int Nb = pre[256];
    const int Npad = (Nb + 63) & ~63;
    for (int k = Nb + t; k < Npad; k += 256) idx[(size_t)b * NHW + k] = 0;
    if (t == 0) { nbArr[b * 2] = Nb; nbArr[b * 2 + 1] = Npad >> 5; }
}

// ---------------------------------------------------------------------------
// Gather K rows and V columns into compacted, PRE-SWIZZLED f16 buffers.
// Kc_sw: row k, 16B unit c16 stored at byte k*512 + ((c16*16) ^ ((k&7)<<4)).
// Vc_sw: row o, within each 32-k chunk unit uin stored at uin ^ ((o>>1)&3).
// grid (64, 8), block 256.
// ---------------------------------------------------------------------------
__global__ __launch_bounds__(256)
void gather_kv(const _Float16* __restrict__ Kws, const float* __restrict__ emb,
               const int* __restrict__ idx, const int* __restrict__ nbArr,
               _Float16* __restrict__ Kc, _Float16* __restrict__ Vc)
{
    const int b = blockIdx.y, k0 = blockIdx.x * 64, t = threadIdx.x;
    const int Nb = nbArr[b * 2];
    const int Npad = (Nb + 63) & ~63;
    if (k0 >= Npad) return;

    __shared__ int sidx[64];
    if (t < 64) sidx[t] = idx[(size_t)b * NHW + k0 + t];
    __syncthreads();

    const _Float16* Kb = Kws + (size_t)b * NHW * OD;
    char* KcB = (char*)(Kc + (size_t)b * NHW * OD);
    #pragma unroll
    for (int r = 0; r < 8; ++r) {
        const int u = r * 256 + t;               // 64 rows x 32 units
        const int row = u >> 5, c16 = u & 31;
        const f16x8 v = *(const f16x8*)(Kb + (size_t)sidx[row] * OD + c16 * 8);
        *(f16x8*)(KcB + (size_t)(k0 + row) * 512 + ((c16 * 16) ^ ((row & 7) << 4))) = v;
    }

    const float* eb = emb + (size_t)b * OD * NHW;
    char* VcB = (char*)(Vc + (size_t)b * OD * NHW);
    #pragma unroll
    for (int r = 0; r < 8; ++r) {
        const int u = r * 256 + t;               // 256 o x 8 units
        const int o = u >> 3, uc = u & 7;
        const int chunk = uc >> 2, uin = uc & 3;
        float4 a, c;
        #pragma unroll
        for (int i = 0; i < 4; ++i) ((float*)&a)[i] = eb[(size_t)o * NHW + sidx[uc * 8 + i]];
        #pragma unroll
        for (int i = 0; i < 4; ++i) ((float*)&c)[i] = eb[(size_t)o * NHW + sidx[uc * 8 + 4 + i]];
        const f16x8 v = cvt8(a, c);
        *(f16x8*)(VcB + (size_t)o * (NHW * 2) + (size_t)k0 * 2 + chunk * 64
                      + ((uin ^ ((o >> 1) & 3)) * 16)) = v;
    }
}

// ---------------------------------------------------------------------------
// Flash attention over compacted support, reg-staged prefetch pipeline.
// grid 512 (b = bid&7 -> one batch per XCD, qt = bid>>3), block 256.
// LDS 36 KB -> 2 blocks/CU.
// ---------------------------------------------------------------------------
__device__ __forceinline__ void load_tile(const char* __restrict__ Kb,
                                          const char* __restrict__ Vb,
                                          int j, int t,
                                          f16x8 (&kst)[4], f16x8 (&vst)[4])
{
    const char* kb = Kb + (size_t)j * (KBLK * 512);
    #pragma unroll
    for (int r = 0; r < 4; ++r)
        kst[r] = *(const f16x8*)(kb + (r * 256 + t) * 16);
    #pragma unroll
    for (int r = 0; r < 4; ++r) {
        const int u = r * 256 + t, o = u >> 2, sl = u & 3;
        vst[r] = *(const f16x8*)(Vb + (size_t)o * (NHW * 2) + (size_t)j * 64 + sl * 16);
    }
}

__global__ __launch_bounds__(256, 2)
void flash_attn(const _Float16* __restrict__ Qws, const _Float16* __restrict__ Kc,
                const _Float16* __restrict__ Vc, const int* __restrict__ nbArr,
                float* __restrict__ outp)
{
    const int bid = blockIdx.x;
    const int b = bid & 7, qt = bid >> 3;
    const int t = threadIdx.x, lane = t & 63, wave = t >> 6;
    const int l16 = lane & 15, lh = lane >> 4;

    __shared__ __align__(16) char Kl[KBLK * 512];   // 16 KB (swizzled layout)
    __shared__ __align__(16) char Vl[OD * 64];      // 16 KB (swizzled layout)
    __shared__ __align__(16) char Pl[4 * 16 * 64];  // 4 KB per-wave P

    const _Float16* Qb = Qws + (size_t)b * NHW * OD;
    const char* Kb = (const char*)(Kc + (size_t)b * NHW * OD);
    const char* Vb = (const char*)(Vc + (size_t)b * OD * NHW);
    const int Nb = nbArr[b * 2];
    const int nt = nbArr[b * 2 + 1];

    f16x8 qf[8];
    {
        const _Float16* qrow = Qb + (size_t)(qt * 64 + wave * 16 + l16) * OD + lh * 8;
        #pragma unroll
        for (int kk = 0; kk < 8; ++kk) qf[kk] = *(const f16x8*)(qrow + kk * 32);
    }

    f32x4 accO[16] = {};
    float M[4] = { -INFINITY, -INFINITY, -INFINITY, -INFINITY };
    float L[4] = { 0.f, 0.f, 0.f, 0.f };

    f16x8 kst[4], vst[4];
    load_tile(Kb, Vb, 0, t, kst, vst);

    #pragma unroll 1
    for (int jt = 0; jt < nt; ++jt) {
        // write current tile regs -> LDS (linear; layouts pre-swizzled)
        #pragma unroll
        for (int r = 0; r < 4; ++r) {
            *(f16x8*)(Kl + (r * 256 + t) * 16) = kst[r];
            *(f16x8*)(Vl + (r * 256 + t) * 16) = vst[r];
        }
        // issue next tile's loads (in flight during compute)
        if (jt + 1 < nt) load_tile(Kb, Vb, jt + 1, t, kst, vst);
        __syncthreads();

        // ---- S = Q K^T : 16 q-rows x 32 j per wave
        f32x4 S[2] = {};
        #pragma unroll
        for (int ct = 0; ct < 2; ++ct) {
            const int row = ct * 16 + l16;
            #pragma unroll
            for (int kk = 0; kk < 8; ++kk) {
                const f16x8 kf = *(const f16x8*)(Kl + row * 512
                                     + ((kk * 64 + lh * 16) ^ ((row & 7) << 4)));
                S[ct] = MFMA16(qf[kk], kf, S[ct]);
            }
        }

        // ---- logits (+tail mask by index)
        float logit[2][4];
        #pragma unroll
        for (int ct = 0; ct < 2; ++ct) {
            const bool val = (jt * 32 + ct * 16 + l16) < Nb;
            #pragma unroll
            for (int r = 0; r < 4; ++r)
                logit[ct][r] = val ? S[ct][r] * 0.25f : -1e30f;
        }

        // ---- row max + deferred rescale (THR=8)
        float tmax[4];
        #pragma unroll
        for (int r = 0; r < 4; ++r) {
            float tm = fmaxf(logit[0][r], logit[1][r]);
            tm = fmaxf(tm, __shfl_xor(tm, 1));
            tm = fmaxf(tm, __shfl_xor(tm, 2));
            tm = fmaxf(tm, __shfl_xor(tm, 4));
            tm = fmaxf(tm, __shfl_xor(tm, 8));
            tmax[r] = tm;
        }
        bool grow = false;
        #pragma unroll
        for (int r = 0; r < 4; ++r) grow = grow || (tmax[r] > M[r] + 8.0f);
        if (__any(grow)) {
            #pragma unroll
            for (int r = 0; r < 4; ++r) {
                const float nm = fmaxf(M[r], tmax[r]);
                const float fac = __expf(M[r] - nm);
                M[r] = nm;
                L[r] *= fac;
                #pragma unroll
                for (int oo = 0; oo < 16; ++oo) accO[oo][r] *= fac;
            }
        }

        // ---- P = exp(logit - M), row sums
        float rowsum[4] = { 0.f, 0.f, 0.f, 0.f };
        _Float16 ph[2][4];
        #pragma unroll
        for (int ct = 0; ct < 2; ++ct)
            #pragma unroll
            for (int r = 0; r < 4; ++r) {
                const float p = __expf(logit[ct][r] - M[r]);
                rowsum[r] += p;
                ph[ct][r] = (_Float16)p;
            }
        #pragma unroll
        for (int r = 0; r < 4; ++r) {
            float s = rowsum[r];
            s += __shfl_xor(s, 1);
            s += __shfl_xor(s, 2);
            s += __shfl_xor(s, 4);
            s += __shfl_xor(s, 8);
            L[r] += s;
        }

        // ---- P -> per-wave LDS (row-XOR swizzle; wave-local, no barrier)
        #pragma unroll
        for (int ct = 0; ct < 2; ++ct)
            #pragma unroll
            for (int r = 0; r < 4; ++r) {
                const int row = lh * 4 + r;
                *(_Float16*)(Pl + wave * 1024 + row * 64
                             + (((ct * 16 + l16) * 2) ^ ((row >> 2) << 4))) = ph[ct][r];
            }

        // ---- O += P V
        const f16x8 pf = *(const f16x8*)(Pl + wave * 1024 + l16 * 64
                                         + ((lh * 16) ^ ((l16 >> 2) << 4)));
        #pragma unroll
        for (int oo = 0; oo < 16; ++oo) {
            const int o = oo * 16 + l16;
            const f16x8 vf = *(const f16x8*)(Vl + o * 64
                                 + ((lh * 16) ^ (((o >> 1) & 3) << 4)));
            accO[oo] = MFMA16(pf, vf, accO[oo]);
        }
        __syncthreads();
    }

    // ---- epilogue
    float rl[4];
    #pragma unroll
    for (int r = 0; r < 4; ++r) rl[r] = 1.0f / fmaxf(L[r], 1e-30f);
    #pragma unroll
    for (int oo = 0; oo < 16; ++oo) {
        const int o = oo * 16 + l16;
        #pragma unroll
        for (int r = 0; r < 4; ++r) {
            const int n = qt * 64 + wave * 16 + lh * 4 + r;
            outp[((size_t)b * OD + o) * NHW + n] = accO[oo][r] * rl[r];
        }
    }
}

extern "C" void kernel_launch(void* const* d_in, const int* in_sizes, int n_in,
                              void* d_out, int out_size, void* d_ws, size_t ws_size,
                              hipStream_t stream) {
    const float* xq   = (const float*)d_in[0];
    const float* xs   = (const float*)d_in[1];
    const float* emb  = (const float*)d_in[2];
    const float* mask = (const float*)d_in[3];
    const float* thw  = (const float*)d_in[4];
    const float* thb  = (const float*)d_in[5];
    const float* phw  = (const float*)d_in[6];
    const float* phb  = (const float*)d_in[7];
    float* out = (float*)d_out;

    const size_t szT = (size_t)BN * NHW * OD;   // elements per f16 tensor
    _Float16* Qws = (_Float16*)d_ws;
    _Float16* Kws = Qws + szT;
    _Float16* Kc  = Kws + szT;
    _Float16* Vc  = Kc + szT;
    _Float16* wf  = Vc + szT;                   // 2*256*512 f16
    int* idxArr   = (int*)(wf + 2 * OD * CIN);
    int* nbArr    = idxArr + (size_t)BN * NHW;

    wcvt<<<dim3(128), 256, 0, stream>>>(thw, phw, wf);
    compact_mask<<<dim3(BN), 256, 0, stream>>>(mask, idxArr, nbArr);
    prep_gemm<<<dim3(64, 16), 256, 0, stream>>>(xq, xs, wf, thb, phb, Qws, Kws);
    gather_kv<<<dim3(64, BN), 256, 0, stream>>>(Kws, emb, idxArr, nbArr, Kc, Vc);
    flash_attn<<<dim3(512), 256, 0, stream>>>(Qws, Kc, Vc, nbArr, out);
}

// Round 6
// 199.387 us; speedup vs baseline: 3.3881x; 1.1903x over previous
//
#include <hip/hip_runtime.h>
#include <hip/hip_fp16.h>
#include <stdint.h>

typedef _Float16 f16x8 __attribute__((ext_vector_type(8)));
typedef _Float16 f16x4 __attribute__((ext_vector_type(4)));
typedef float    f32x4 __attribute__((ext_vector_type(4)));

#define MFMA16(a, b, c) __builtin_amdgcn_mfma_f32_16x16x32_f16(a, b, c, 0, 0, 0)

static constexpr int BN   = 8;
static constexpr int CIN  = 512;
static constexpr int NHW  = 4096;
static constexpr int OD   = 256;
static constexpr int KBLK = 32;

// 128B-row XOR swizzle (prep LDS tiles)
#define RSWZ(row, cb) ((((row) << 7)) + ((cb) ^ (((row) & 7) << 4)))

__device__ __forceinline__ f16x8 cvt8(const float4 a, const float4 b) {
    f16x8 r;
    r[0] = (_Float16)a.x; r[1] = (_Float16)a.y; r[2] = (_Float16)a.z; r[3] = (_Float16)a.w;
    r[4] = (_Float16)b.x; r[5] = (_Float16)b.y; r[6] = (_Float16)b.z; r[7] = (_Float16)b.w;
    return r;
}

__device__ __forceinline__ uint32_t pkh2(float x, float y) {
    union { _Float16 h[2]; uint32_t u; } z;
    z.h[0] = (_Float16)x; z.h[1] = (_Float16)y;
    return z.u;
}

// ---------------------------------------------------------------------------
// Convert theta/phi weights to f16 once. wf[sel][o][c], 256x512 each.
// ---------------------------------------------------------------------------
__global__ __launch_bounds__(256)
void wcvt(const float* __restrict__ thw, const float* __restrict__ phw,
          _Float16* __restrict__ wf)
{
    const int i = blockIdx.x * 256 + threadIdx.x;   // 32768 float4 units
    const float4 a = ((const float4*)thw)[i];
    const float4 b = ((const float4*)phw)[i];
    f16x4 ra, rb;
    ra[0] = (_Float16)a.x; ra[1] = (_Float16)a.y; ra[2] = (_Float16)a.z; ra[3] = (_Float16)a.w;
    rb[0] = (_Float16)b.x; rb[1] = (_Float16)b.y; rb[2] = (_Float16)b.z; rb[3] = (_Float16)b.w;
    *(f16x4*)(wf + (size_t)i * 4)          = ra;
    *(f16x4*)(wf + 131072 + (size_t)i * 4) = rb;
}

// ---------------------------------------------------------------------------
// Prep: T[b][n][o] = sum_c x[b][c][n]*w[o][c] + bias[o] -> f16 [n][256].
// grid (64 nt, 16 = b*2+sel), block 256. x read ONCE; full o=256 per block.
// ---------------------------------------------------------------------------
__global__ __launch_bounds__(256)
void prep_gemm(const float* __restrict__ xq, const float* __restrict__ xs,
               const _Float16* __restrict__ wf,
               const float* __restrict__ thb, const float* __restrict__ phb,
               _Float16* __restrict__ Qws, _Float16* __restrict__ Kws)
{
    const int nt = blockIdx.x, z = blockIdx.y;
    const int b = z >> 1, sel = z & 1;
    const float* x        = (sel ? xs : xq) + (size_t)b * CIN * NHW;
    const _Float16* w     = wf + (size_t)sel * (OD * CIN);
    const float* bias     = sel ? phb : thb;
    _Float16* out         = (sel ? Kws : Qws) + (size_t)b * NHW * OD;
    const int n0 = nt * 64;

    __shared__ __align__(16) char Xs[64 * 128];    // [n][c-chunk 64] f16, swizzled
    __shared__ __align__(16) char Ws[256 * 128];   // [o][c-chunk 64] f16, swizzled

    const int t    = threadIdx.x;
    const int lane = t & 63, wave = t >> 6;
    const int l16  = lane & 15, lh = lane >> 4;

    f32x4 acc[4][4] = {};   // [oo][nn]: rows o = wave*64+oo*16+4lh+r, cols n = nn*16+l16

    for (int c0 = 0; c0 < CIN; c0 += 64) {
        // stage Xs: transpose x[c][n] -> Xs[n][c]
        #pragma unroll
        for (int rep = 0; rep < 4; ++rep) {
            const int ci = rep * 16 + (t >> 4);
            const int nl = (t & 15) * 4;
            const float4 v = *(const float4*)&x[(size_t)(c0 + ci) * NHW + n0 + nl];
            *(_Float16*)(Xs + RSWZ(nl + 0, ci * 2)) = (_Float16)v.x;
            *(_Float16*)(Xs + RSWZ(nl + 1, ci * 2)) = (_Float16)v.y;
            *(_Float16*)(Xs + RSWZ(nl + 2, ci * 2)) = (_Float16)v.z;
            *(_Float16*)(Xs + RSWZ(nl + 3, ci * 2)) = (_Float16)v.w;
        }
        // stage Ws: all 256 o rows, this c-chunk (f16 source)
        #pragma unroll
        for (int r = 0; r < 8; ++r) {
            const int u = r * 256 + t;
            const int o = u >> 3, cs8 = (u & 7) * 8;
            const f16x8 v = *(const f16x8*)(w + (size_t)o * CIN + c0 + cs8);
            *(f16x8*)(Ws + RSWZ(o, cs8 * 2)) = v;
        }
        __syncthreads();

        #pragma unroll
        for (int kk = 0; kk < 2; ++kk) {
            f16x8 af[4];
            #pragma unroll
            for (int oo = 0; oo < 4; ++oo)
                af[oo] = *(const f16x8*)(Ws + RSWZ(wave * 64 + oo * 16 + l16, kk * 64 + lh * 16));
            #pragma unroll
            for (int nn = 0; nn < 4; ++nn) {
                const f16x8 bf = *(const f16x8*)(Xs + RSWZ(nn * 16 + l16, kk * 64 + lh * 16));
                #pragma unroll
                for (int oo = 0; oo < 4; ++oo)
                    acc[oo][nn] = MFMA16(af[oo], bf, acc[oo][nn]);
            }
        }
        __syncthreads();
    }

    // epilogue: lane holds o = wave*64+oo*16+lh*4+r, n = nn*16+l16 -> f16x4 stores
    #pragma unroll
    for (int oo = 0; oo < 4; ++oo) {
        const float4 bi = *(const float4*)&bias[wave * 64 + oo * 16 + lh * 4];
        #pragma unroll
        for (int nn = 0; nn < 4; ++nn) {
            f16x4 v;
            v[0] = (_Float16)(acc[oo][nn][0] + bi.x);
            v[1] = (_Float16)(acc[oo][nn][1] + bi.y);
            v[2] = (_Float16)(acc[oo][nn][2] + bi.z);
            v[3] = (_Float16)(acc[oo][nn][3] + bi.w);
            const int n = n0 + nn * 16 + l16;
            *(f16x4*)&out[(size_t)n * OD + wave * 64 + oo * 16 + lh * 4] = v;
        }
    }
}

// ---------------------------------------------------------------------------
// Compact mask (ordered). idx[b][k] = source n of k-th unmasked pixel (0-pad
// to Npad=ceil64(Nb)); nbArr[b*2]=Nb, nbArr[b*2+1]=Npad/32 (flash tile count).
// ---------------------------------------------------------------------------
__global__ __launch_bounds__(256)
void compact_mask(const float* __restrict__ mask, int* __restrict__ idx,
                  int* __restrict__ nbArr)
{
    const int b = blockIdx.x, t = threadIdx.x;
    const float* mb = mask + (size_t)b * NHW;
    __shared__ int cnt[256];
    __shared__ int pre[257];

    const int base = t * 16;
    float mv[16];
    int c = 0;
    #pragma unroll
    for (int i = 0; i < 16; ++i) { mv[i] = mb[base + i]; c += (mv[i] != 0.0f); }
    cnt[t] = c;
    __syncthreads();
    if (t == 0) {
        int s = 0;
        for (int i = 0; i < 256; ++i) { pre[i] = s; s += cnt[i]; }
        pre[256] = s;
    }
    __syncthreads();
    int o = pre[t];
    #pragma unroll
    for (int i = 0; i < 16; ++i)
        if (mv[i] != 0.0f) idx[(size_t)b * NHW + o++] = base + i;

    const int Nb = pre[256];
    const int Npad = (Nb + 63) & ~63;
    for (int k = Nb + t; k < Npad; k += 256) idx[(size_t)b * NHW + k] = 0;
    if (t == 0) { nbArr[b * 2] = Nb; nbArr[b * 2 + 1] = Npad >> 5; }
}

// ---------------------------------------------------------------------------
// Gather K rows and V columns into compacted, PRE-SWIZZLED f16 buffers.
// Kc_sw: row k, 16B unit c16 stored at byte k*512 + ((c16*16) ^ ((k&7)<<4)).
// Vc_sw: row o, within each 32-k chunk unit uin stored at uin ^ ((o>>1)&3).
// grid (64, 8), block 256.
// ---------------------------------------------------------------------------
__global__ __launch_bounds__(256)
void gather_kv(const _Float16* __restrict__ Kws, const float* __restrict__ emb,
               const int* __restrict__ idx, const int* __restrict__ nbArr,
               _Float16* __restrict__ Kc, _Float16* __restrict__ Vc)
{
    const int b = blockIdx.y, k0 = blockIdx.x * 64, t = threadIdx.x;
    const int Nb = nbArr[b * 2];
    const int Npad = (Nb + 63) & ~63;
    if (k0 >= Npad) return;

    __shared__ int sidx[64];
    if (t < 64) sidx[t] = idx[(size_t)b * NHW + k0 + t];
    __syncthreads();

    const _Float16* Kb = Kws + (size_t)b * NHW * OD;
    char* KcB = (char*)(Kc + (size_t)b * NHW * OD);
    #pragma unroll
    for (int r = 0; r < 8; ++r) {
        const int u = r * 256 + t;               // 64 rows x 32 units
        const int row = u >> 5, c16 = u & 31;
        const f16x8 v = *(const f16x8*)(Kb + (size_t)sidx[row] * OD + c16 * 8);
        *(f16x8*)(KcB + (size_t)(k0 + row) * 512 + ((c16 * 16) ^ ((row & 7) << 4))) = v;
    }

    const float* eb = emb + (size_t)b * OD * NHW;
    char* VcB = (char*)(Vc + (size_t)b * OD * NHW);
    #pragma unroll
    for (int r = 0; r < 8; ++r) {
        const int u = r * 256 + t;               // 256 o x 8 units
        const int o = u >> 3, uc = u & 7;
        const int chunk = uc >> 2, uin = uc & 3;
        float4 a, c;
        #pragma unroll
        for (int i = 0; i < 4; ++i) ((float*)&a)[i] = eb[(size_t)o * NHW + sidx[uc * 8 + i]];
        #pragma unroll
        for (int i = 0; i < 4; ++i) ((float*)&c)[i] = eb[(size_t)o * NHW + sidx[uc * 8 + 4 + i]];
        const f16x8 v = cvt8(a, c);
        *(f16x8*)(VcB + (size_t)o * (NHW * 2) + (size_t)k0 * 2 + chunk * 64
                      + ((uin ^ ((o >> 1) & 3)) * 16)) = v;
    }
}

// ---------------------------------------------------------------------------
// Flash attention, swapped-operand QK^T (lane-local q-row softmax), register
// P re-fragmentation (no P LDS bounce), double-buffered K/V LDS (1 barrier).
// grid 512 (b = bid&7 -> one batch per XCD, qt = bid>>3), block 256.
// LDS 64 KB -> 2 blocks/CU.
// ---------------------------------------------------------------------------
__device__ __forceinline__ void load_tile(const char* __restrict__ Kb,
                                          const char* __restrict__ Vb,
                                          int j, int t,
                                          f16x8 (&kst)[4], f16x8 (&vst)[4])
{
    const char* kb = Kb + (size_t)j * (KBLK * 512);
    #pragma unroll
    for (int r = 0; r < 4; ++r)
        kst[r] = *(const f16x8*)(kb + (r * 256 + t) * 16);
    #pragma unroll
    for (int r = 0; r < 4; ++r) {
        const int u = r * 256 + t, o = u >> 2, sl = u & 3;
        vst[r] = *(const f16x8*)(Vb + (size_t)o * (NHW * 2) + (size_t)j * 64 + sl * 16);
    }
}

__global__ __launch_bounds__(256, 2)
void flash_attn(const _Float16* __restrict__ Qws, const _Float16* __restrict__ Kc,
                const _Float16* __restrict__ Vc, const int* __restrict__ nbArr,
                float* __restrict__ outp)
{
    const int bid = blockIdx.x;
    const int b = bid & 7, qt = bid >> 3;
    const int t = threadIdx.x, lane = t & 63, wave = t >> 6;
    const int l16 = lane & 15, lh = lane >> 4;

    __shared__ __align__(16) char Kl[2][KBLK * 512];   // 2 x 16 KB (swizzled)
    __shared__ __align__(16) char Vl[2][OD * 64];      // 2 x 16 KB (swizzled)

    const _Float16* Qb = Qws + (size_t)b * NHW * OD;
    const char* Kb = (const char*)(Kc + (size_t)b * NHW * OD);
    const char* Vb = (const char*)(Vc + (size_t)b * OD * NHW);
    const int Nb = nbArr[b * 2];
    const int nt = nbArr[b * 2 + 1];

    // Q fragments: lane l16 = q-row (this wave's 16 rows), elems c = kk*32+8lh..
    f16x8 qf[8];
    {
        const _Float16* qrow = Qb + (size_t)(qt * 64 + wave * 16 + l16) * OD + lh * 8;
        #pragma unroll
        for (int kk = 0; kk < 8; ++kk) qf[kk] = *(const f16x8*)(qrow + kk * 32);
    }

    f32x4 accO[16] = {};            // D[o][q]: rows o = oo*16+4lh+r, col q = l16
    float M = -INFINITY, L = 0.f;   // per-lane: this lane's q-row state

    f16x8 kst[4], vst[4];
    load_tile(Kb, Vb, 0, t, kst, vst);
    #pragma unroll
    for (int r = 0; r < 4; ++r) {
        *(f16x8*)(Kl[0] + (r * 256 + t) * 16) = kst[r];
        *(f16x8*)(Vl[0] + (r * 256 + t) * 16) = vst[r];
    }
    if (nt > 1) load_tile(Kb, Vb, 1, t, kst, vst);
    __syncthreads();

    #pragma unroll 1
    for (int jt = 0; jt < nt; ++jt) {
        const int cur = jt & 1;
        // ---- stage next tile regs -> other buffer
        if (jt + 1 < nt) {
            #pragma unroll
            for (int r = 0; r < 4; ++r) {
                *(f16x8*)(Kl[cur ^ 1] + (r * 256 + t) * 16) = kst[r];
                *(f16x8*)(Vl[cur ^ 1] + (r * 256 + t) * 16) = vst[r];
            }
        }
        // ---- issue loads for tile jt+2
        if (jt + 2 < nt) load_tile(Kb, Vb, jt + 2, t, kst, vst);

        // ---- S' = K Q^T (swapped): D[k][q], lane l16 = q, rows k = ct*16+4lh+r
        f32x4 S[2] = {};
        #pragma unroll
        for (int ct = 0; ct < 2; ++ct) {
            const int row = ct * 16 + l16;
            #pragma unroll
            for (int kk = 0; kk < 8; ++kk) {
                const f16x8 kf = *(const f16x8*)(Kl[cur] + row * 512
                                     + ((kk * 64 + lh * 16) ^ ((row & 7) << 4)));
                S[ct] = MFMA16(kf, qf[kk], S[ct]);
            }
        }

        // ---- logits
        float lg[8];
        #pragma unroll
        for (int ct = 0; ct < 2; ++ct)
            #pragma unroll
            for (int r = 0; r < 4; ++r)
                lg[ct * 4 + r] = S[ct][r] * 0.25f;
        if (jt * 32 + 32 > Nb) {   // tail tile: mask pad columns
            #pragma unroll
            for (int ct = 0; ct < 2; ++ct)
                #pragma unroll
                for (int r = 0; r < 4; ++r) {
                    const int kg = jt * 32 + ct * 16 + lh * 4 + r;
                    if (kg >= Nb) lg[ct * 4 + r] = -1e30f;
                }
        }

        // ---- per-lane row max (in-reg 8 + 2 shfl)
        float m8 = fmaxf(fmaxf(fmaxf(lg[0], lg[1]), fmaxf(lg[2], lg[3])),
                         fmaxf(fmaxf(lg[4], lg[5]), fmaxf(lg[6], lg[7])));
        m8 = fmaxf(m8, __shfl_xor(m8, 16));
        m8 = fmaxf(m8, __shfl_xor(m8, 32));

        // ---- deferred rescale (THR=8)
        if (__any(m8 > M + 8.0f)) {
            const float nm = fmaxf(M, m8);
            const float fac = __expf(M - nm);
            M = nm; L *= fac;
            #pragma unroll
            for (int oo = 0; oo < 16; ++oo)
                #pragma unroll
                for (int r = 0; r < 4; ++r) accO[oo][r] *= fac;
        }

        // ---- P = exp(lg - M), row sum
        float p[8];
        float s = 0.f;
        #pragma unroll
        for (int i = 0; i < 8; ++i) { p[i] = __expf(lg[i] - M); s += p[i]; }
        s += __shfl_xor(s, 16);
        s += __shfl_xor(s, 32);
        L += s;

        // ---- re-fragment P: source lane (l16=q, lh') holds k = 4lh'+r (ps0/ps1)
        //      and k = 16+4lh'+r (ps2/ps3). Dest lane (l16=q, lh) needs
        //      k = 8lh+j. Pull BOTH halves from the two source lanes, select
        //      by DEST lh&2 after the shuffle (pull semantics: the shuffled
        //      expression is evaluated on the SOURCE lane).
        const uint32_t ps0 = pkh2(p[0], p[1]), ps1 = pkh2(p[2], p[3]);
        const uint32_t ps2 = pkh2(p[4], p[5]), ps3 = pkh2(p[6], p[7]);
        const int src0 = l16 + (((2 * lh) & 3) << 4);
        const int src1 = src0 + 16;
        const uint32_t q0 = __shfl(ps0, src0), q2 = __shfl(ps2, src0);
        const uint32_t q1 = __shfl(ps1, src0), q3 = __shfl(ps3, src0);
        const uint32_t r0 = __shfl(ps0, src1), r2 = __shfl(ps2, src1);
        const uint32_t r1 = __shfl(ps1, src1), r3 = __shfl(ps3, src1);
        const bool hi = (lh & 2) != 0;
        union { uint32_t u[4]; f16x8 v; } pu;
        pu.u[0] = hi ? q2 : q0;
        pu.u[1] = hi ? q3 : q1;
        pu.u[2] = hi ? r2 : r0;
        pu.u[3] = hi ? r3 : r1;
        const f16x8 pf = pu.v;

        // ---- O += V^T P : D[o][q], A = V^T rows o, B = P cols q
        #pragma unroll
        for (int oo = 0; oo < 16; ++oo) {
            const int o = oo * 16 + l16;
            const f16x8 vf = *(const f16x8*)(Vl[cur] + o * 64
                                 + ((lh * 16) ^ (((o >> 1) & 3) << 4)));
            accO[oo] = MFMA16(vf, pf, accO[oo]);
        }
        __syncthreads();
    }

    // ---- epilogue: lane l16 = q -> n; rows o = oo*16+lh*4+r
    const float rl = 1.0f / fmaxf(L, 1e-30f);
    const int n = qt * 64 + wave * 16 + l16;
    #pragma unroll
    for (int oo = 0; oo < 16; ++oo) {
        #pragma unroll
        for (int r = 0; r < 4; ++r) {
            const int o = oo * 16 + lh * 4 + r;
            outp[((size_t)b * OD + o) * NHW + n] = accO[oo][r] * rl;
        }
    }
}

extern "C" void kernel_launch(void* const* d_in, const int* in_sizes, int n_in,
                              void* d_out, int out_size, void* d_ws, size_t ws_size,
                              hipStream_t stream) {
    const float* xq   = (const float*)d_in[0];
    const float* xs   = (const float*)d_in[1];
    const float* emb  = (const float*)d_in[2];
    const float* mask = (const float*)d_in[3];
    const float* thw  = (const float*)d_in[4];
    const float* thb  = (const float*)d_in[5];
    const float* phw  = (const float*)d_in[6];
    const float* phb  = (const float*)d_in[7];
    float* out = (float*)d_out;

    const size_t szT = (size_t)BN * NHW * OD;   // elements per f16 tensor
    _Float16* Qws = (_Float16*)d_ws;
    _Float16* Kws = Qws + szT;
    _Float16* Kc  = Kws + szT;
    _Float16* Vc  = Kc + szT;
    _Float16* wf  = Vc + szT;                   // 2*256*512 f16
    int* idxArr   = (int*)(wf + 2 * OD * CIN);
    int* nbArr    = idxArr + (size_t)BN * NHW;

    wcvt<<<dim3(128), 256, 0, stream>>>(thw, phw, wf);
    compact_mask<<<dim3(BN), 256, 0, stream>>>(mask, idxArr, nbArr);
    prep_gemm<<<dim3(64, 16), 256, 0, stream>>>(xq, xs, wf, thb, phb, Qws, Kws);
    gather_kv<<<dim3(64, BN), 256, 0, stream>>>(Kws, emb, idxArr, nbArr, Kc, Vc);
    flash_attn<<<dim3(512), 256, 0, stream>>>(Qws, Kc, Vc, nbArr, out);
}